// Round 3
// baseline (4403.453 us; speedup 1.0000x reference)
//
#include <hip/hip_runtime.h>
#include <math.h>

#define N_USERS 100000
#define N_ITEMS 50000
#define N_NODES 150000
#define EMB 64
#define NI 128
#define NUM_EDGES 4000000
#define NPAD 150016            // 586 * 256
#define NB 586                 // buckets of 256 nodes
#define ETILE 4096             // edges per block in count/scatter
#define EGRID ((NUM_EDGES + ETILE - 1) / ETILE)   // 977

// ---- count: per-node degree (global atomics) + per-bucket histogram (LDS->global)

__global__ __launch_bounds__(256) void count_kernel(const int* __restrict__ h,
                                                    int* __restrict__ cnt,
                                                    int* __restrict__ bcnt) {
    __shared__ int lb[NB];
    int tid = threadIdx.x;
    for (int i = tid; i < NB; i += 256) lb[i] = 0;
    __syncthreads();
    int base = blockIdx.x * ETILE;
#pragma unroll
    for (int k = 0; k < ETILE / 256; ++k) {
        int idx = base + k * 256 + tid;
        if (idx < NUM_EDGES) {
            int v = h[idx];
            atomicAdd(&cnt[v], 1);
            atomicAdd(&lb[v >> 8], 1);
        }
    }
    __syncthreads();
    for (int i = tid; i < NB; i += 256) {
        int c = lb[i];
        if (c) atomicAdd(&bcnt[i], c);
    }
}

__global__ void dinv_kernel(const int* __restrict__ cnt, float* __restrict__ dinv) {
    int i = blockIdx.x * blockDim.x + threadIdx.x;
    if (i < NPAD) {
        int c = cnt[i];
        dinv[i] = (c > 0) ? rsqrtf((float)c) : 0.0f;
    }
}

// ---- scan bucket counts -> bstart (exclusive) and gcur (running cursors)

__global__ __launch_bounds__(1024) void scan_kernel(const int* __restrict__ bcnt,
                                                    int* __restrict__ bstart,
                                                    int* __restrict__ gcur) {
    __shared__ int s[1024];
    int tid = threadIdx.x;
    int v = (tid < NB) ? bcnt[tid] : 0;
    s[tid] = v;
    __syncthreads();
    for (int off = 1; off < 1024; off <<= 1) {
        int t = (tid >= off) ? s[tid - off] : 0;
        __syncthreads();
        s[tid] += t;
        __syncthreads();
    }
    if (tid < NB) {
        int excl = s[tid] - v;
        bstart[tid] = excl;
        gcur[tid] = excl;
    }
    if (tid == NB - 1) bstart[NB] = s[tid];
}

// ---- bucket scatter: block-aggregated reservation; pack edge as (h&255)<<18 | t

__global__ __launch_bounds__(256) void bucket_scatter(const int* __restrict__ h,
                                                      const int* __restrict__ t,
                                                      int* __restrict__ gcur,
                                                      unsigned int* __restrict__ ebuf) {
    __shared__ int lc[NB];
    __shared__ int lbase[NB];
    __shared__ int lcur[NB];
    int tid = threadIdx.x;
    for (int i = tid; i < NB; i += 256) lc[i] = 0;
    __syncthreads();
    int base = blockIdx.x * ETILE;
#pragma unroll
    for (int k = 0; k < ETILE / 256; ++k) {
        int idx = base + k * 256 + tid;
        if (idx < NUM_EDGES) atomicAdd(&lc[h[idx] >> 8], 1);
    }
    __syncthreads();
    for (int i = tid; i < NB; i += 256) {
        int c = lc[i];
        lbase[i] = c ? atomicAdd(&gcur[i], c) : 0;
        lcur[i] = 0;
    }
    __syncthreads();
#pragma unroll
    for (int k = 0; k < ETILE / 256; ++k) {
        int idx = base + k * 256 + tid;
        if (idx < NUM_EDGES) {
            int hh = h[idx], tt = t[idx];
            int b = hh >> 8;
            int p = lbase[b] + atomicAdd(&lcur[b], 1);
            ebuf[p] = ((unsigned int)(hh & 255) << 18) | (unsigned int)tt;
        }
    }
}

// ---- init: embs = concat(user,item); acc(d_out) = embs

__global__ void init_kernel(const float* __restrict__ ue, const float* __restrict__ ie,
                            float* __restrict__ embs, float* __restrict__ acc) {
    int i = blockIdx.x * blockDim.x + threadIdx.x;
    const int uelems = N_USERS * EMB / 4;
    const int total  = N_NODES * EMB / 4;
    if (i < total) {
        float4 v = (i < uelems) ? ((const float4*)ue)[i] : ((const float4*)ie)[i - uelems];
        ((float4*)embs)[i] = v;
        ((float4*)acc)[i]  = v;
    }
}

// ---- SpMM: per-bucket LDS accumulation, work-stealing over buckets.
// acc[256 rows][64 dims] fp32 in LDS (64 KB -> 2 blocks/CU, 16 waves/CU).

__global__ __launch_bounds__(512) void spmm_lds(const int* __restrict__ bstart,
                                                const unsigned int* __restrict__ ebuf,
                                                const float* __restrict__ dinv,
                                                const float* __restrict__ embs,
                                                float* __restrict__ gnn,
                                                int* __restrict__ ctr) {
    __shared__ float acc[256 * EMB];
    __shared__ float dl[256];
    __shared__ int bsh;
    int tid = threadIdx.x;
    int wid = tid >> 6;
    int lane = tid & 63;

    for (;;) {
        if (tid == 0) bsh = atomicAdd(ctr, 1);
        __syncthreads();                 // also guards prev iter's LDS reads
        int b = bsh;
        if (b >= NB) break;
        int nb = b << 8;

        float4* a4 = (float4*)acc;
        float4 z = {0.f, 0.f, 0.f, 0.f};
        for (int i = tid; i < 256 * EMB / 4; i += 512) a4[i] = z;
        if (tid < 256) dl[tid] = dinv[nb + tid];
        __syncthreads();

        int s = bstart[b], e = bstart[b + 1];
#pragma unroll 4
        for (int i = s + wid; i < e; i += 8) {
            unsigned int q = ebuf[i];          // wave-uniform
            int tt = (int)(q & 0x3FFFFu);
            int hl = (int)(q >> 18);
            float gv = dinv[tt];
            float v = embs[(size_t)tt * EMB + lane];
            atomicAdd(&acc[hl * EMB + lane], gv * v);
        }
        __syncthreads();

        float4* g4 = (float4*)(gnn + (size_t)nb * EMB);
        for (int i = tid; i < 256 * EMB / 4; i += 512) {
            float4 v = a4[i];
            float dr = dl[i >> 4];
            v.x *= dr; v.y *= dr; v.z *= dr; v.w *= dr;
            g4[i] = v;
        }
        // loop-top barrier separates writeout from next zero
    }
}

// ---- intent head + combine (unchanged)

__global__ __launch_bounds__(256) void intent_kernel(const float* __restrict__ W,
                                                     const float* __restrict__ gnn,
                                                     float* __restrict__ embs,
                                                     float* __restrict__ acc,
                                                     float scale) {
    __shared__ float Wt[NI * 65];    // Wt[c*65+d] = W[d*128+c]
    __shared__ float esm[4][EMB];
    __shared__ float pr[4][NI];

    for (int i = threadIdx.x; i < EMB * NI; i += blockDim.x) {
        int d = i >> 7, c = i & 127;
        Wt[c * 65 + d] = W[i];
    }
    __syncthreads();

    int wave = threadIdx.x >> 6;
    int lane = threadIdx.x & 63;
    int row  = blockIdx.x * 4 + wave;

    esm[wave][lane] = embs[row * EMB + lane];
    __syncthreads();

    float s0 = 0.0f, s1 = 0.0f;
    const float* w0 = &Wt[lane * 65];
    const float* w1 = &Wt[(lane + 64) * 65];
    const float* er = esm[wave];
#pragma unroll 8
    for (int d = 0; d < EMB; ++d) {
        float ed = er[d];
        s0 = fmaf(ed, w0[d], s0);
        s1 = fmaf(ed, w1[d], s1);
    }

    float m = fmaxf(s0, s1);
    for (int o = 32; o > 0; o >>= 1) m = fmaxf(m, __shfl_xor(m, o));
    float e0 = __expf(s0 - m), e1 = __expf(s1 - m);
    float sum = e0 + e1;
    for (int o = 32; o > 0; o >>= 1) sum += __shfl_xor(sum, o);
    float inv = 1.0f / sum;
    pr[wave][lane]      = e0 * inv;
    pr[wave][lane + 64] = e1 * inv;
    __syncthreads();

    float o = 0.0f;
    const float* pw = pr[wave];
#pragma unroll 8
    for (int c = 0; c < NI; ++c) o = fmaf(pw[c], Wt[c * 65 + lane], o);

    int idx = row * EMB + lane;
    float nv = gnn[idx] + o;
    embs[idx] = nv;
    acc[idx] = (acc[idx] + nv) * scale;
}

// ---- launch ----

extern "C" void kernel_launch(void* const* d_in, const int* in_sizes, int n_in,
                              void* d_out, int out_size, void* d_ws, size_t ws_size,
                              hipStream_t stream) {
    const float* ue = (const float*)d_in[0];
    const float* ie = (const float*)d_in[1];
    const float* W  = (const float*)d_in[2];
    const int*   h  = (const int*)d_in[3];
    const int*   t  = (const int*)d_in[4];
    float* out = (float*)d_out;

    // workspace layout (4-byte units)
    int*          cnt    = (int*)d_ws;                    // NPAD
    int*          bcnt   = cnt + NPAD;                    // NB
    int*          ctr2   = bcnt + 592;                    // 2 (within memset range)
    int*          bstart = cnt + NPAD + 1024;             // NB+1
    int*          gcur   = bstart + 640;                  // NB
    float*        dinv   = (float*)(gcur + 640);          // NPAD
    unsigned int* ebuf   = (unsigned int*)(dinv + NPAD);  // NUM_EDGES
    float*        embs   = (float*)(ebuf + NUM_EDGES);    // NPAD*64
    float*        gnn    = embs + (size_t)NPAD * EMB;     // NPAD*64

    // zero cnt + bcnt + ctr2 in one memset
    hipMemsetAsync(cnt, 0, (NPAD + 1024) * sizeof(int), stream);

    count_kernel<<<EGRID, 256, 0, stream>>>(h, cnt, bcnt);
    dinv_kernel<<<(NPAD + 255) / 256, 256, 0, stream>>>(cnt, dinv);
    scan_kernel<<<1, 1024, 0, stream>>>(bcnt, bstart, gcur);
    bucket_scatter<<<EGRID, 256, 0, stream>>>(h, t, gcur, ebuf);
    init_kernel<<<(N_NODES * EMB / 4 + 255) / 256, 256, 0, stream>>>(ue, ie, embs, out);

    for (int layer = 0; layer < 2; ++layer) {
        spmm_lds<<<512, 512, 0, stream>>>(bstart, ebuf, dinv, embs, gnn, ctr2 + layer);
        float scale = (layer == 1) ? (1.0f / 3.0f) : 1.0f;
        intent_kernel<<<N_NODES / 4, 256, 0, stream>>>(W, gnn, embs, out, scale);
    }
}

// Round 4
// 957.528 us; speedup vs baseline: 4.5988x; 4.5988x over previous
//
#include <hip/hip_runtime.h>
#include <math.h>

#define N_USERS 100000
#define N_ITEMS 50000
#define N_NODES 150000
#define EMB 64
#define NI 128
#define NUM_EDGES 4000000
#define NPAD 150016            // 586 * 256
#define NB 586                 // buckets of 256 nodes
#define BMAX 8192              // max edges per bucket (mean 6827, sigma ~83)
#define ETILE 4096
#define EGRID ((NUM_EDGES + ETILE - 1) / ETILE)   // 977

// ---- bucket histogram (586 coarse counters, LDS-aggregated) ----

__global__ __launch_bounds__(256) void bcount_kernel(const int* __restrict__ h,
                                                     int* __restrict__ bcnt) {
    __shared__ int lb[NB];
    int tid = threadIdx.x;
    for (int i = tid; i < NB; i += 256) lb[i] = 0;
    __syncthreads();
    int base = blockIdx.x * ETILE;
#pragma unroll
    for (int k = 0; k < ETILE / 256; ++k) {
        int idx = base + k * 256 + tid;
        if (idx < NUM_EDGES) atomicAdd(&lb[h[idx] >> 8], 1);
    }
    __syncthreads();
    for (int i = tid; i < NB; i += 256) {
        int c = lb[i];
        if (c) atomicAdd(&bcnt[i], c);
    }
}

// ---- scan bucket counts -> bstart (exclusive) + gcur cursors ----

__global__ __launch_bounds__(1024) void scan_kernel(const int* __restrict__ bcnt,
                                                    int* __restrict__ bstart,
                                                    int* __restrict__ gcur) {
    __shared__ int s[1024];
    int tid = threadIdx.x;
    int v = (tid < NB) ? bcnt[tid] : 0;
    s[tid] = v;
    __syncthreads();
    for (int off = 1; off < 1024; off <<= 1) {
        int t = (tid >= off) ? s[tid - off] : 0;
        __syncthreads();
        s[tid] += t;
        __syncthreads();
    }
    if (tid < NB) {
        int excl = s[tid] - v;
        bstart[tid] = excl;
        gcur[tid] = excl;
    }
    if (tid == NB - 1) bstart[NB] = s[tid];
}

// ---- bucket scatter: block-aggregated reservations; pack (h&255)<<18 | t ----

__global__ __launch_bounds__(256) void bucket_scatter(const int* __restrict__ h,
                                                      const int* __restrict__ t,
                                                      int* __restrict__ gcur,
                                                      unsigned int* __restrict__ ebuf) {
    __shared__ int lc[NB];
    __shared__ int lbase[NB];
    __shared__ int lcur[NB];
    int tid = threadIdx.x;
    for (int i = tid; i < NB; i += 256) lc[i] = 0;
    __syncthreads();
    int base = blockIdx.x * ETILE;
#pragma unroll
    for (int k = 0; k < ETILE / 256; ++k) {
        int idx = base + k * 256 + tid;
        if (idx < NUM_EDGES) atomicAdd(&lc[h[idx] >> 8], 1);
    }
    __syncthreads();
    for (int i = tid; i < NB; i += 256) {
        int c = lc[i];
        lbase[i] = c ? atomicAdd(&gcur[i], c) : 0;
        lcur[i] = 0;
    }
    __syncthreads();
#pragma unroll
    for (int k = 0; k < ETILE / 256; ++k) {
        int idx = base + k * 256 + tid;
        if (idx < NUM_EDGES) {
            int hh = h[idx], tt = t[idx];
            int b = hh >> 8;
            int p = lbase[b] + atomicAdd(&lcur[b], 1);
            ebuf[p] = ((unsigned int)(hh & 255) << 18) | (unsigned int)tt;
        }
    }
}

// ---- per-bucket in-LDS counting sort -> sorted col (in place), row_ptr, dinv ----

__global__ __launch_bounds__(256) void bucket_csr(const int* __restrict__ bstart,
                                                  unsigned int* __restrict__ ebuf,
                                                  int* __restrict__ row_ptr,
                                                  float* __restrict__ dinv) {
    __shared__ unsigned int in_s[BMAX];
    __shared__ unsigned int out_s[BMAX];
    __shared__ int cnt_s[256];
    __shared__ int base_s[256];
    __shared__ int sc[256];
    int b = blockIdx.x, tid = threadIdx.x;
    int s = bstart[b], e = bstart[b + 1], n = e - s;

    for (int i = tid; i < n; i += 256) in_s[i] = ebuf[s + i];
    cnt_s[tid] = 0;
    __syncthreads();
    for (int i = tid; i < n; i += 256) atomicAdd(&cnt_s[in_s[i] >> 18], 1);
    __syncthreads();

    int c = cnt_s[tid];
    sc[tid] = c;
    __syncthreads();
    for (int off = 1; off < 256; off <<= 1) {
        int tv = (tid >= off) ? sc[tid - off] : 0;
        __syncthreads();
        sc[tid] += tv;
        __syncthreads();
    }
    int excl = sc[tid] - c;
    base_s[tid] = excl;
    int node = (b << 8) + tid;
    row_ptr[node] = s + excl;
    dinv[node] = (c > 0) ? rsqrtf((float)c) : 0.0f;
    cnt_s[tid] = 0;      // reuse as cursors
    __syncthreads();

    for (int i = tid; i < n; i += 256) {
        unsigned int q = in_s[i];
        int hl = (int)(q >> 18);
        int p = base_s[hl] + atomicAdd(&cnt_s[hl], 1);
        out_s[p] = q & 0x3FFFFu;
    }
    __syncthreads();
    for (int i = tid; i < n; i += 256) ebuf[s + i] = out_s[i];   // now pure t, row-sorted
}

// ---- init: embs = concat(user,item); acc(d_out) = embs ----

__global__ void init_kernel(const float* __restrict__ ue, const float* __restrict__ ie,
                            float* __restrict__ embs, float* __restrict__ acc) {
    int i = blockIdx.x * blockDim.x + threadIdx.x;
    const int uelems = N_USERS * EMB / 4;
    const int total  = N_NODES * EMB / 4;
    if (i < total) {
        float4 v = (i < uelems) ? ((const float4*)ue)[i] : ((const float4*)ie)[i - uelems];
        ((float4*)embs)[i] = v;
        ((float4*)acc)[i]  = v;
    }
}

// ---- fused SpMM (CSR gather) + intent head + combine ----
// One wave per row (grid-stride, ~18 rows/wave). Lane = dim. Wt staged once per
// block (stride-65 pad -> both phases conflict-free). Per-wave LDS scratch, no
// barriers in the row loop (wave-synchronous; compiler inserts lgkmcnt waits).

__global__ __launch_bounds__(256) void spmm_intent(const int* __restrict__ row_ptr,
                                                   const int* __restrict__ col,
                                                   const float* __restrict__ dinv,
                                                   const float* __restrict__ ein,
                                                   float* __restrict__ eout,
                                                   const float* __restrict__ W,
                                                   float* __restrict__ acc, float scale) {
    __shared__ float Wt[NI * 65];    // Wt[c*65+d] = W[d*128+c]
    __shared__ float esm[4][EMB];
    __shared__ float pr[4][NI];
    int tid = threadIdx.x;
    for (int i = tid; i < EMB * NI; i += 256) {
        int d = i >> 7, c = i & 127;
        Wt[c * 65 + d] = W[i];
    }
    __syncthreads();

    int w = tid >> 6, lane = tid & 63;
    const float* w0 = &Wt[lane * 65];
    const float* w1 = &Wt[(lane + 64) * 65];
    float* er = esm[w];
    float* pw = pr[w];

    for (int row = blockIdx.x * 4 + w; row < N_NODES; row += 8192) {
        int s = row_ptr[row], e = row_ptr[row + 1];
        float a0 = 0.0f, a1 = 0.0f;
        int i = s;
        for (; i + 3 < e; i += 4) {
            int c0 = col[i], c1 = col[i + 1], c2 = col[i + 2], c3 = col[i + 3];
            float g0 = dinv[c0], g1 = dinv[c1], g2 = dinv[c2], g3 = dinv[c3];
            float v0 = ein[(size_t)c0 * EMB + lane];
            float v1 = ein[(size_t)c1 * EMB + lane];
            float v2 = ein[(size_t)c2 * EMB + lane];
            float v3 = ein[(size_t)c3 * EMB + lane];
            a0 = fmaf(g0, v0, a0); a1 = fmaf(g1, v1, a1);
            a0 = fmaf(g2, v2, a0); a1 = fmaf(g3, v3, a1);
        }
        for (; i < e; ++i) {
            int c0 = col[i];
            a0 = fmaf(dinv[c0], ein[(size_t)c0 * EMB + lane], a0);
        }
        float gnnv = (a0 + a1) * dinv[row];

        float eo = ein[(size_t)row * EMB + lane];
        er[lane] = eo;
        float s0 = 0.0f, s1 = 0.0f;
#pragma unroll 16
        for (int d = 0; d < EMB; ++d) {
            float ed = er[d];
            s0 = fmaf(ed, w0[d], s0);
            s1 = fmaf(ed, w1[d], s1);
        }
        float m = fmaxf(s0, s1);
        for (int o = 32; o > 0; o >>= 1) m = fmaxf(m, __shfl_xor(m, o));
        float e0 = __expf(s0 - m), e1 = __expf(s1 - m);
        float sum = e0 + e1;
        for (int o = 32; o > 0; o >>= 1) sum += __shfl_xor(sum, o);
        float inv = 1.0f / sum;
        pw[lane]      = e0 * inv;
        pw[lane + 64] = e1 * inv;
        float o = 0.0f;
#pragma unroll 16
        for (int c = 0; c < NI; ++c) o = fmaf(pw[c], Wt[c * 65 + lane], o);

        size_t idx = (size_t)row * EMB + lane;
        float nv = gnnv + o;
        eout[idx] = nv;
        acc[idx] = (acc[idx] + nv) * scale;
    }
}

// ---- launch ----

extern "C" void kernel_launch(void* const* d_in, const int* in_sizes, int n_in,
                              void* d_out, int out_size, void* d_ws, size_t ws_size,
                              hipStream_t stream) {
    const float* ue = (const float*)d_in[0];
    const float* ie = (const float*)d_in[1];
    const float* W  = (const float*)d_in[2];
    const int*   h  = (const int*)d_in[3];
    const int*   t  = (const int*)d_in[4];
    float* out = (float*)d_out;

    // workspace layout (4-byte units), total ~94 MB
    int*          bcnt    = (int*)d_ws;                    // 1024
    int*          bstart  = bcnt + 1024;                   // 640 (need NB+1)
    int*          gcur    = bstart + 640;                  // 640
    int*          row_ptr = gcur + 640;                    // NPAD + 16
    float*        dinv    = (float*)(row_ptr + NPAD + 16); // NPAD
    unsigned int* ebuf    = (unsigned int*)(dinv + NPAD);  // NUM_EDGES (becomes col)
    float*        embsA   = (float*)(ebuf + NUM_EDGES);    // NPAD*64
    float*        embsB   = embsA + (size_t)NPAD * EMB;    // NPAD*64

    hipMemsetAsync(bcnt, 0, 1024 * sizeof(int), stream);
    bcount_kernel<<<EGRID, 256, 0, stream>>>(h, bcnt);
    scan_kernel<<<1, 1024, 0, stream>>>(bcnt, bstart, gcur);
    bucket_scatter<<<EGRID, 256, 0, stream>>>(h, t, gcur, ebuf);
    bucket_csr<<<NB, 256, 0, stream>>>(bstart, ebuf, row_ptr, dinv);
    init_kernel<<<(N_NODES * EMB / 4 + 255) / 256, 256, 0, stream>>>(ue, ie, embsA, out);

    const int* col = (const int*)ebuf;
    spmm_intent<<<2048, 256, 0, stream>>>(row_ptr, col, dinv, embsA, embsB, W, out, 1.0f);
    spmm_intent<<<2048, 256, 0, stream>>>(row_ptr, col, dinv, embsB, embsA, W, out, 1.0f / 3.0f);
}